// Round 3
// baseline (637.905 us; speedup 1.0000x reference)
//
#include <hip/hip_runtime.h>
#include <hip/hip_bf16.h>

#define FEAT 256
#define HID 128
#define CLASSES 32
#define LAYERS 3

typedef float f4 __attribute__((ext_vector_type(4)));
typedef float f2 __attribute__((ext_vector_type(2)));
typedef __attribute__((ext_vector_type(8))) short short8;
typedef __attribute__((ext_vector_type(4))) float f32x4;

// split fp32 into bf16 hi + bf16 lo (RNE); v - hf is exact in fp32
__device__ __forceinline__ void split_bf16(float v, short& hi, short& lo) {
    unsigned u = __float_as_uint(v);
    unsigned r = (u + 0x7FFF + ((u >> 16) & 1)) >> 16;
    hi = (short)r;
    float hf = __uint_as_float(r << 16);
    float d = v - hf;
    unsigned u2 = __float_as_uint(d);
    unsigned r2 = (u2 + 0x7FFF + ((u2 >> 16) & 1)) >> 16;
    lo = (short)r2;
}

// ---------------- CSR build ----------------

__global__ void count_kernel(const int* __restrict__ dst, int* __restrict__ counts, int E) {
    int e = blockIdx.x * blockDim.x + threadIdx.x;
    if (e < E) atomicAdd(&counts[dst[e]], 1);
}

__global__ void partial_kernel(const int* __restrict__ counts, int* __restrict__ partials, int N) {
    int t = threadIdx.x;
    int i = blockIdx.x * 256 + t;
    int v = (i < N) ? counts[i] : 0;
#pragma unroll
    for (int off = 32; off >= 1; off >>= 1) v += __shfl_down(v, off, 64);
    __shared__ int ws[4];
    if ((t & 63) == 0) ws[t >> 6] = v;
    __syncthreads();
    if (t == 0) partials[blockIdx.x] = ws[0] + ws[1] + ws[2] + ws[3];
}

__global__ void scan_partials_kernel(const int* __restrict__ partials, int* __restrict__ poff, int NB) {
    int t = threadIdx.x, lane = t & 63, w = t >> 6;
    int v = (t < NB) ? partials[t] : 0;
    int x = v;
#pragma unroll
    for (int off = 1; off < 64; off <<= 1) {
        int y = __shfl_up(x, off, 64);
        if (lane >= off) x += y;
    }
    __shared__ int ws[4];
    if (lane == 63) ws[w] = x;
    __syncthreads();
    int woff = 0;
    for (int k = 0; k < w; ++k) woff += ws[k];
    if (t < NB) poff[t] = woff + x - v;
}

__global__ void scan_final_kernel(const int* __restrict__ counts, const int* __restrict__ poff,
                                  int* __restrict__ row_off, int* __restrict__ cursor, int N) {
    int t = threadIdx.x, lane = t & 63, w = t >> 6;
    int i = blockIdx.x * 256 + t;
    int v = (i < N) ? counts[i] : 0;
    int x = v;
#pragma unroll
    for (int off = 1; off < 64; off <<= 1) {
        int y = __shfl_up(x, off, 64);
        if (lane >= off) x += y;
    }
    __shared__ int ws[4];
    if (lane == 63) ws[w] = x;
    __syncthreads();
    int woff = 0;
    for (int k = 0; k < w; ++k) woff += ws[k];
    int excl = poff[blockIdx.x] + woff + x - v;
    if (i < N) {
        row_off[i] = excl;
        cursor[i] = excl;
        if (i == N - 1) row_off[N] = excl + v;
    }
}

__global__ void fill_kernel(const int* __restrict__ src, const int* __restrict__ dst,
                            int* __restrict__ cursor, int* __restrict__ csr_src, int E) {
    int e = blockIdx.x * blockDim.x + threadIdx.x;
    if (e < E) {
        int pos = atomicAdd(&cursor[dst[e]], 1);
        csr_src[pos] = src[e];
    }
}

// ---------------- weight prep: transposed bf16 hi/lo tables ----------------
__global__ void prep_emb_kernel(const float* __restrict__ emb_w,
                                unsigned short* __restrict__ hi, unsigned short* __restrict__ lo) {
    int idx = blockIdx.x * 256 + threadIdx.x;  // 128*256
    if (idx >= 128 * 256) return;
    int n = idx >> 8, k = idx & 255;
    short h, l;
    split_bf16(emb_w[k * 128 + n], h, l);
    hi[n * 256 + k] = (unsigned short)h;
    lo[n * 256 + k] = (unsigned short)l;
}

__global__ void prep_layer_kernel(const float* __restrict__ rel_w, const float* __restrict__ root_w,
                                  unsigned short* __restrict__ hi, unsigned short* __restrict__ lo) {
    int idx = blockIdx.x * 256 + threadIdx.x;  // 3*128*256
    if (idx >= 3 * 128 * 256) return;
    int l = idx >> 15;
    int r = idx & 32767;
    int n = r >> 8, k = r & 255;
    float w = (k < 128) ? rel_w[l * 16384 + k * 128 + n] : root_w[l * 16384 + (k - 128) * 128 + n];
    short h, lw;
    split_bf16(w, h, lw);
    hi[idx] = (unsigned short)h;
    lo[idx] = (unsigned short)lw;
}

__global__ void prep_head_kernel(const float* __restrict__ head_w,
                                 unsigned short* __restrict__ hi, unsigned short* __restrict__ lo) {
    int idx = blockIdx.x * 256 + threadIdx.x;  // 64*128
    if (idx >= 64 * 128) return;
    int c = idx >> 7, k = idx & 127;
    float w = (c < 32) ? head_w[k * 32 + c] : head_w[(128 + k) * 32 + (c - 32)];
    short h, l;
    split_bf16(w, h, l);
    hi[c * 128 + k] = (unsigned short)h;
    lo[c * 128 + k] = (unsigned short)l;
}

// ---------------- MFMA split-bf16 GEMM (LDS-free, barrier-free) ----------------
// out[M x NCOL] = act( concatK(A0|A1)[M x KTOT] @ W[KTOT x NCOL] + bias )
// W given pre-transposed bf16 hi/lo: Whi/Wlo[n][k] (n-major, stride KTOT).
// Block = 256 threads = 4 waves; wave w owns rows [blk*64 + w*16, +16) x all NCOL cols.
// 16 rows/wave (not 32): grid 2x bigger -> ~3 blocks/CU, latency hidden by TLP.
// A chunk for kc+1 is prefetched before the MFMA cluster of kc (ILP).
template <int NCOL, int KTOT, bool RELU>
__global__ __launch_bounds__(256) void gemm_mfma(
    const float* __restrict__ A0, int lda0,
    const float* __restrict__ A1, int lda1, int K0,
    const unsigned short* __restrict__ Whi, const unsigned short* __restrict__ Wlo,
    const float* __restrict__ bias, float* __restrict__ out, int M) {
    constexpr int NCHUNK = KTOT / 32;
    constexpr int NCT = NCOL / 16;  // 8 (NCOL=128) or 4 (NCOL=64)
    int wv = threadIdx.x >> 6;
    int lane = threadIdx.x & 63;
    int m16 = lane & 15;
    int quad = lane >> 4;
    int rowbase = blockIdx.x * 64 + wv * 16;

    int arow = rowbase + m16;
    arow = (arow < M) ? arow : (M - 1);  // clamp reads; stores guarded below

    f32x4 acc[NCT] = {};
    float bcol[NCT];
#pragma unroll
    for (int ct = 0; ct < NCT; ++ct) bcol[ct] = bias ? bias[ct * 16 + m16] : 0.f;

    // address of this lane's 8-float A slice for chunk kc
    auto aptr = [&](int kc) {
        bool second = (kc * 32 >= K0);
        const float* Ab = second ? A1 : A0;
        int lda = second ? lda1 : lda0;
        int kofs = kc * 32 - (second ? K0 : 0);
        return Ab + (size_t)arow * lda + kofs + quad * 8;
    };

    const float* p0 = aptr(0);
    f4 ra0 = *(const f4*)p0;
    f4 ra1 = *(const f4*)(p0 + 4);

#pragma unroll
    for (int kc = 0; kc < NCHUNK; ++kc) {
        // convert current chunk in-register
        float av[8] = {ra0[0], ra0[1], ra0[2], ra0[3], ra1[0], ra1[1], ra1[2], ra1[3]};
        short8 Ah, Al;
#pragma unroll
        for (int j = 0; j < 8; ++j) {
            short h, l;
            split_bf16(av[j], h, l);
            Ah[j] = h;
            Al[j] = l;
        }

        // prefetch next chunk's raw A while MFMAs below run
        f4 na0 = ra0, na1 = ra1;
        if (kc + 1 < NCHUNK) {
            const float* pn = aptr(kc + 1);
            na0 = *(const f4*)pn;
            na1 = *(const f4*)(pn + 4);
        }

        // B fragments direct from global (L2-resident weight tables), 3-pass MFMA
#pragma unroll
        for (int ct = 0; ct < NCT; ++ct) {
            size_t wb = (size_t)(ct * 16 + m16) * KTOT + kc * 32 + quad * 8;
            short8 Bh = *(const short8*)(Whi + wb);
            short8 Bl = *(const short8*)(Wlo + wb);
            acc[ct] = __builtin_amdgcn_mfma_f32_16x16x32_bf16(Ah, Bh, acc[ct], 0, 0, 0);
            acc[ct] = __builtin_amdgcn_mfma_f32_16x16x32_bf16(Al, Bh, acc[ct], 0, 0, 0);
            acc[ct] = __builtin_amdgcn_mfma_f32_16x16x32_bf16(Ah, Bl, acc[ct], 0, 0, 0);
        }

        ra0 = na0;
        ra1 = na1;
    }

    // epilogue: C/D layout col = lane&15, row = quad*4 + reg
#pragma unroll
    for (int r = 0; r < 4; ++r) {
        int row = rowbase + quad * 4 + r;
        if (row < M) {
#pragma unroll
            for (int ct = 0; ct < NCT; ++ct) {
                float v = acc[ct][r] + bcol[ct];
                out[(size_t)row * NCOL + ct * 16 + m16] = RELU ? fmaxf(v, 0.f) : v;
            }
        }
    }
}

// ---------------- aggregation (CSR gather-sum, 4-wide pipelined MLP) ----------------
__global__ void aggregate_kernel(const float* __restrict__ x, const int* __restrict__ row_off,
                                 const int* __restrict__ csr, float* __restrict__ agg, int N) {
    int gw = (blockIdx.x * 256 + threadIdx.x) >> 6;
    int lane = threadIdx.x & 63;
    if (gw >= N) return;
    int beg = row_off[gw], end = row_off[gw + 1];
    int cofs = lane * 2;

    f2 a0 = (f2)0.f, a1 = (f2)0.f, a2 = (f2)0.f, a3 = (f2)0.f;

    int nfull = (end - beg) >> 2;
    int j = beg;
    if (nfull > 0) {
        int s0 = csr[j], s1 = csr[j + 1], s2 = csr[j + 2], s3 = csr[j + 3];
        for (int b = 1; b < nfull; ++b) {
            f2 v0 = *(const f2*)&x[(size_t)s0 * HID + cofs];
            f2 v1 = *(const f2*)&x[(size_t)s1 * HID + cofs];
            f2 v2 = *(const f2*)&x[(size_t)s2 * HID + cofs];
            f2 v3 = *(const f2*)&x[(size_t)s3 * HID + cofs];
            int jn = j + 4;
            s0 = csr[jn]; s1 = csr[jn + 1]; s2 = csr[jn + 2]; s3 = csr[jn + 3];
            a0 += v0; a1 += v1; a2 += v2; a3 += v3;
            j = jn;
        }
        f2 v0 = *(const f2*)&x[(size_t)s0 * HID + cofs];
        f2 v1 = *(const f2*)&x[(size_t)s1 * HID + cofs];
        f2 v2 = *(const f2*)&x[(size_t)s2 * HID + cofs];
        f2 v3 = *(const f2*)&x[(size_t)s3 * HID + cofs];
        a0 += v0; a1 += v1; a2 += v2; a3 += v3;
        j += 4;
    }

    int rem = end - j;
    if (rem > 0) {
        int e1 = end - 1;
        int t0 = csr[j];
        int t1 = csr[min(j + 1, e1)];
        int t2 = csr[min(j + 2, e1)];
        f2 w0 = *(const f2*)&x[(size_t)t0 * HID + cofs];
        f2 w1 = *(const f2*)&x[(size_t)t1 * HID + cofs];
        f2 w2 = *(const f2*)&x[(size_t)t2 * HID + cofs];
        a0 += w0;
        if (rem > 1) a1 += w1;
        if (rem > 2) a2 += w2;
    }

    f2 a = (a0 + a2) + (a1 + a3);
    *(f2*)&agg[(size_t)gw * HID + cofs] = a;
}

// ---------------- edge head ----------------
__global__ void edge_out_kernel(const int* __restrict__ src, const int* __restrict__ dst,
                                const float* __restrict__ pspd, const float* __restrict__ head_b,
                                float* __restrict__ out, int E) {
    int idx = blockIdx.x * blockDim.x + threadIdx.x;
    int e = idx >> 3;
    int c4 = (idx & 7) * 4;
    if (e >= E) return;
    int s = src[e], d = dst[e];
    f4 a = *(const f4*)&pspd[(size_t)s * 64 + c4];
    f4 b = *(const f4*)&pspd[(size_t)d * 64 + 32 + c4];
    f4 hb = *(const f4*)&head_b[c4];
    f4 o = a + b + hb;
    *(f4*)&out[(size_t)e * CLASSES + c4] = o;
}

// ---------------- launcher ----------------

extern "C" void kernel_launch(void* const* d_in, const int* in_sizes, int n_in,
                              void* d_out, int out_size, void* d_ws, size_t ws_size,
                              hipStream_t stream) {
    const float* feat   = (const float*)d_in[0];
    const int*   eidx   = (const int*)d_in[1];
    const float* emb_w  = (const float*)d_in[2];
    const float* emb_b  = (const float*)d_in[3];
    const float* rel_w  = (const float*)d_in[4];
    const float* rel_b  = (const float*)d_in[5];
    const float* root_w = (const float*)d_in[6];
    const float* head_w = (const float*)d_in[7];
    const float* head_b = (const float*)d_in[8];
    float* out = (float*)d_out;

    int N = in_sizes[0] / FEAT;
    int E = in_sizes[1] / 2;
    const int* src = eidx;
    const int* dst = eidx + E;

    // workspace layout: floats, then ints, then ushort weight tables (16B-aligned)
    float* xA  = (float*)d_ws;               // N*128
    float* xB  = xA + (size_t)N * HID;       // N*128
    float* agg = xB + (size_t)N * HID;       // N*128 (pspd reuses as N*64)
    int* counts   = (int*)(agg + (size_t)N * HID);  // N
    int* row_off  = counts + N;                     // N+1
    int* cursor   = row_off + (N + 1);              // N
    int* csr_src  = cursor + N;                     // E
    int* partials = csr_src + E;                    // 256
    int* poff     = partials + 256;                 // 256
    int* iend     = poff + 256;
    // pad int region to 16B boundary
    size_t ioff = (size_t)(iend - (int*)d_ws);
    ioff = (ioff + 3) & ~(size_t)3;
    unsigned short* we_hi = (unsigned short*)((int*)d_ws + ioff);
    unsigned short* we_lo = we_hi + 128 * 256;
    unsigned short* wl_hi = we_lo + 128 * 256;      // 3*128*256
    unsigned short* wl_lo = wl_hi + 3 * 128 * 256;  // 3*128*256
    unsigned short* wp_hi = wl_lo + 3 * 128 * 256;  // 64*128
    unsigned short* wp_lo = wp_hi + 64 * 128;       // 64*128

    int NB = (N + 255) / 256;

    hipMemsetAsync(counts, 0, (size_t)N * sizeof(int), stream);
    count_kernel<<<(E + 255) / 256, 256, 0, stream>>>(dst, counts, E);
    partial_kernel<<<NB, 256, 0, stream>>>(counts, partials, N);
    scan_partials_kernel<<<1, 256, 0, stream>>>(partials, poff, NB);
    scan_final_kernel<<<NB, 256, 0, stream>>>(counts, poff, row_off, cursor, N);
    fill_kernel<<<(E + 255) / 256, 256, 0, stream>>>(src, dst, cursor, csr_src, E);

    prep_emb_kernel<<<(128 * 256 + 255) / 256, 256, 0, stream>>>(emb_w, we_hi, we_lo);
    prep_layer_kernel<<<(3 * 128 * 256 + 255) / 256, 256, 0, stream>>>(rel_w, root_w, wl_hi, wl_lo);
    prep_head_kernel<<<(64 * 128 + 255) / 256, 256, 0, stream>>>(head_w, wp_hi, wp_lo);

    int grid = (N + 63) / 64;
    // embed: x = relu(feat @ emb_w + emb_b)
    gemm_mfma<HID, FEAT, true><<<grid, 256, 0, stream>>>(
        feat, FEAT, nullptr, 0, FEAT, we_hi, we_lo, emb_b, xA, N);

    const float* xin = xA;
    float* xout = xB;
    for (int l = 0; l < LAYERS; ++l) {
        aggregate_kernel<<<(N * 64 + 255) / 256, 256, 0, stream>>>(xin, row_off, csr_src, agg, N);
        gemm_mfma<HID, 2 * HID, true><<<grid, 256, 0, stream>>>(
            agg, HID, xin, HID, HID,
            wl_hi + (size_t)l * 128 * 256, wl_lo + (size_t)l * 128 * 256,
            rel_b + (size_t)l * HID, xout, N);
        float* tmp = (float*)xin; xin = xout; xout = tmp;
    }

    // pspd = x @ Wpp (no bias/relu); reuse agg
    float* pspd = agg;
    gemm_mfma<64, HID, false><<<grid, 256, 0, stream>>>(
        xin, HID, nullptr, 0, HID, wp_hi, wp_lo, nullptr, pspd, N);

    edge_out_kernel<<<((size_t)E * 8 + 255) / 256, 256, 0, stream>>>(src, dst, pspd, head_b, out, E);
}

// Round 4
// 438.222 us; speedup vs baseline: 1.4557x; 1.4557x over previous
//
#include <hip/hip_runtime.h>
#include <hip/hip_bf16.h>

#define FEAT 256
#define HID 128
#define CLASSES 32
#define LAYERS 3

typedef float f4 __attribute__((ext_vector_type(4)));
typedef float f2 __attribute__((ext_vector_type(2)));
typedef __attribute__((ext_vector_type(8))) short short8;
typedef __attribute__((ext_vector_type(4))) float f32x4;

// split fp32 into bf16 hi + bf16 lo (RNE); v - hf is exact in fp32
__device__ __forceinline__ void split_bf16(float v, short& hi, short& lo) {
    unsigned u = __float_as_uint(v);
    unsigned r = (u + 0x7FFF + ((u >> 16) & 1)) >> 16;
    hi = (short)r;
    float hf = __uint_as_float(r << 16);
    float d = v - hf;
    unsigned u2 = __float_as_uint(d);
    unsigned r2 = (u2 + 0x7FFF + ((u2 >> 16) & 1)) >> 16;
    lo = (short)r2;
}

// ---------------- CSR build ----------------

__global__ void count_kernel(const int* __restrict__ dst, int* __restrict__ counts, int E) {
    int e = blockIdx.x * blockDim.x + threadIdx.x;
    if (e < E) atomicAdd(&counts[dst[e]], 1);
}

__global__ void partial_kernel(const int* __restrict__ counts, int* __restrict__ partials, int N) {
    int t = threadIdx.x;
    int i = blockIdx.x * 256 + t;
    int v = (i < N) ? counts[i] : 0;
#pragma unroll
    for (int off = 32; off >= 1; off >>= 1) v += __shfl_down(v, off, 64);
    __shared__ int ws[4];
    if ((t & 63) == 0) ws[t >> 6] = v;
    __syncthreads();
    if (t == 0) partials[blockIdx.x] = ws[0] + ws[1] + ws[2] + ws[3];
}

__global__ void scan_partials_kernel(const int* __restrict__ partials, int* __restrict__ poff, int NB) {
    int t = threadIdx.x, lane = t & 63, w = t >> 6;
    int v = (t < NB) ? partials[t] : 0;
    int x = v;
#pragma unroll
    for (int off = 1; off < 64; off <<= 1) {
        int y = __shfl_up(x, off, 64);
        if (lane >= off) x += y;
    }
    __shared__ int ws[4];
    if (lane == 63) ws[w] = x;
    __syncthreads();
    int woff = 0;
    for (int k = 0; k < w; ++k) woff += ws[k];
    if (t < NB) poff[t] = woff + x - v;
}

__global__ void scan_final_kernel(const int* __restrict__ counts, const int* __restrict__ poff,
                                  int* __restrict__ row_off, int* __restrict__ cursor, int N) {
    int t = threadIdx.x, lane = t & 63, w = t >> 6;
    int i = blockIdx.x * 256 + t;
    int v = (i < N) ? counts[i] : 0;
    int x = v;
#pragma unroll
    for (int off = 1; off < 64; off <<= 1) {
        int y = __shfl_up(x, off, 64);
        if (lane >= off) x += y;
    }
    __shared__ int ws[4];
    if (lane == 63) ws[w] = x;
    __syncthreads();
    int woff = 0;
    for (int k = 0; k < w; ++k) woff += ws[k];
    int excl = poff[blockIdx.x] + woff + x - v;
    if (i < N) {
        row_off[i] = excl;
        cursor[i] = excl;
        if (i == N - 1) row_off[N] = excl + v;
    }
}

__global__ void fill_kernel(const int* __restrict__ src, const int* __restrict__ dst,
                            int* __restrict__ cursor, int* __restrict__ csr_src, int E) {
    int e = blockIdx.x * blockDim.x + threadIdx.x;
    if (e < E) {
        int pos = atomicAdd(&cursor[dst[e]], 1);
        csr_src[pos] = src[e];
    }
}

// ---------------- weight prep: transposed bf16 hi/lo tables ----------------
__global__ void prep_emb_kernel(const float* __restrict__ emb_w,
                                unsigned short* __restrict__ hi, unsigned short* __restrict__ lo) {
    int idx = blockIdx.x * 256 + threadIdx.x;  // 128*256
    if (idx >= 128 * 256) return;
    int n = idx >> 8, k = idx & 255;
    short h, l;
    split_bf16(emb_w[k * 128 + n], h, l);
    hi[n * 256 + k] = (unsigned short)h;
    lo[n * 256 + k] = (unsigned short)l;
}

__global__ void prep_layer_kernel(const float* __restrict__ rel_w, const float* __restrict__ root_w,
                                  unsigned short* __restrict__ hi, unsigned short* __restrict__ lo) {
    int idx = blockIdx.x * 256 + threadIdx.x;  // 3*128*256
    if (idx >= 3 * 128 * 256) return;
    int l = idx >> 15;
    int r = idx & 32767;
    int n = r >> 8, k = r & 255;
    float w = (k < 128) ? rel_w[l * 16384 + k * 128 + n] : root_w[l * 16384 + (k - 128) * 128 + n];
    short h, lw;
    split_bf16(w, h, lw);
    hi[idx] = (unsigned short)h;
    lo[idx] = (unsigned short)lw;
}

__global__ void prep_head_kernel(const float* __restrict__ head_w,
                                 unsigned short* __restrict__ hi, unsigned short* __restrict__ lo) {
    int idx = blockIdx.x * 256 + threadIdx.x;  // 64*128
    if (idx >= 64 * 128) return;
    int c = idx >> 7, k = idx & 127;
    float w = (c < 32) ? head_w[k * 32 + c] : head_w[(128 + k) * 32 + (c - 32)];
    short h, l;
    split_bf16(w, h, l);
    hi[c * 128 + k] = (unsigned short)h;
    lo[c * 128 + k] = (unsigned short)l;
}

// ---------------- MFMA split-bf16 GEMM with LDS-staged B ----------------
// out[M x NCOL] = act( concatK(A0|A1)[M x KTOT] @ W[KTOT x NCOL] + bias )
// W pre-transposed bf16 hi/lo: Whi/Wlo[n][k] (n-major, stride KTOT).
// Block = 256 threads = 4 waves; wave w owns rows [blk*128 + w*32, +32).
// Per K-chunk (32), B (all NCOL cols, hi+lo) is staged ONCE per block into LDS
// (reg-staged: global->reg issued one chunk ahead, ds_write at top of iter).
// LDS layout: [table][col][64B chunk-slice]; lane (m16,quad) b128-reads are
// bank-balanced (8 lanes per 4-bank group x 8 phases = minimum). A is
// register-prefetched one chunk ahead; split_bf16 conversion overlaps the
// in-flight global loads (issued before the barrier).
template <int NCOL, int KTOT, bool RELU>
__global__ __launch_bounds__(256) void gemm_mfma(
    const float* __restrict__ A0, int lda0,
    const float* __restrict__ A1, int lda1, int K0,
    const unsigned short* __restrict__ Whi, const unsigned short* __restrict__ Wlo,
    const float* __restrict__ bias, float* __restrict__ out, int M) {
    constexpr int NCHUNK = KTOT / 32;
    constexpr int NCT = NCOL / 16;     // 8 (NCOL=128) or 4 (NCOL=64)
    constexpr int CB = NCOL * 128;     // LDS bytes per chunk (hi+lo), 16KB / 8KB
    constexpr int NI = NCT * 2;        // 1KB stage instrs per chunk (per block)
    constexpr int NIW = NI / 4;        // per wave: 4 or 2

    __shared__ unsigned char lds[CB];

    int wv = threadIdx.x >> 6;
    int lane = threadIdx.x & 63;
    int m16 = lane & 15;
    int quad = lane >> 4;
    int rowbase = blockIdx.x * 128 + wv * 32;

    int arow[2];
#pragma unroll
    for (int rt = 0; rt < 2; ++rt) {
        int r = rowbase + rt * 16 + m16;
        arow[rt] = (r < M) ? r : (M - 1);  // clamp reads; stores guarded below
    }

    // stage instr i: table t=i&1, cols [(i>>1)*16, +16); lane covers col=cb+(lane>>2), quarter lane&3
    auto g_src = [&](int i, int kc) -> const unsigned short* {
        const unsigned short* W = (i & 1) ? Wlo : Whi;
        int cb = (i >> 1) * 16;
        return W + (size_t)(cb + (lane >> 2)) * KTOT + kc * 32 + (lane & 3) * 8;
    };
    auto l_dst = [&](int i) -> unsigned char* {
        int t = i & 1;
        int cb = (i >> 1) * 16;
        return lds + t * (NCOL * 64) + cb * 64 + lane * 16;
    };
    auto aptr = [&](int kc, int rt) -> const float* {
        bool second = (kc * 32 >= K0);
        const float* Ab = second ? A1 : A0;
        int lda = second ? lda1 : lda0;
        int kofs = kc * 32 - (second ? K0 : 0);
        return Ab + (size_t)arow[rt] * lda + kofs + quad * 8;
    };

    f32x4 acc[2][NCT] = {};
    float bcol[NCT];
#pragma unroll
    for (int ct = 0; ct < NCT; ++ct) bcol[ct] = bias ? bias[ct * 16 + m16] : 0.f;

    // prologue: issue chunk-0 B-stage loads and A loads
    f4 stg[NIW];
#pragma unroll
    for (int ii = 0; ii < NIW; ++ii) stg[ii] = *(const f4*)(const void*)g_src(wv * NIW + ii, 0);
    f4 ra[2][2];
#pragma unroll
    for (int rt = 0; rt < 2; ++rt) {
        const float* p = aptr(0, rt);
        ra[rt][0] = *(const f4*)p;
        ra[rt][1] = *(const f4*)(p + 4);
    }

#pragma unroll
    for (int kc = 0; kc < NCHUNK; ++kc) {
        // 1. commit staged B for this chunk to LDS (waits on stg's loads)
#pragma unroll
        for (int ii = 0; ii < NIW; ++ii) *(f4*)(void*)l_dst(wv * NIW + ii) = stg[ii];

        // 2. issue next chunk's global loads (B stage + A) -- fly during convert+MFMA
        f4 na[2][2];
        if (kc + 1 < NCHUNK) {
#pragma unroll
            for (int ii = 0; ii < NIW; ++ii) stg[ii] = *(const f4*)(const void*)g_src(wv * NIW + ii, kc + 1);
#pragma unroll
            for (int rt = 0; rt < 2; ++rt) {
                const float* p = aptr(kc + 1, rt);
                na[rt][0] = *(const f4*)p;
                na[rt][1] = *(const f4*)(p + 4);
            }
        }

        // 3. convert current A in-register (overlaps in-flight loads)
        short8 Ah[2], Al[2];
#pragma unroll
        for (int rt = 0; rt < 2; ++rt) {
            float av[8] = {ra[rt][0][0], ra[rt][0][1], ra[rt][0][2], ra[rt][0][3],
                           ra[rt][1][0], ra[rt][1][1], ra[rt][1][2], ra[rt][1][3]};
#pragma unroll
            for (int j = 0; j < 8; ++j) {
                short h, l;
                split_bf16(av[j], h, l);
                Ah[rt][j] = h;
                Al[rt][j] = l;
            }
        }

        __syncthreads();  // B stage visible to all waves

        // 4. compute from LDS: per ct, 2 ds_read_b128 + 6 MFMAs
#pragma unroll
        for (int ct = 0; ct < NCT; ++ct) {
            const unsigned char* ph = lds + (ct * 16 + m16) * 64 + quad * 16;
            short8 Bh = *(const short8*)(const void*)ph;
            short8 Bl = *(const short8*)(const void*)(ph + NCOL * 64);
#pragma unroll
            for (int rt = 0; rt < 2; ++rt) {
                acc[rt][ct] = __builtin_amdgcn_mfma_f32_16x16x32_bf16(Ah[rt], Bh, acc[rt][ct], 0, 0, 0);
                acc[rt][ct] = __builtin_amdgcn_mfma_f32_16x16x32_bf16(Al[rt], Bh, acc[rt][ct], 0, 0, 0);
                acc[rt][ct] = __builtin_amdgcn_mfma_f32_16x16x32_bf16(Ah[rt], Bl, acc[rt][ct], 0, 0, 0);
            }
        }

        if (kc + 1 < NCHUNK) {
#pragma unroll
            for (int rt = 0; rt < 2; ++rt) {
                ra[rt][0] = na[rt][0];
                ra[rt][1] = na[rt][1];
            }
        }

        __syncthreads();  // all waves done reading before next iter's ds_write
    }

    // epilogue: C/D layout col = lane&15, row = quad*4 + reg
#pragma unroll
    for (int rt = 0; rt < 2; ++rt) {
#pragma unroll
        for (int r = 0; r < 4; ++r) {
            int row = rowbase + rt * 16 + quad * 4 + r;
            if (row < M) {
#pragma unroll
                for (int ct = 0; ct < NCT; ++ct) {
                    float v = acc[rt][ct][r] + bcol[ct];
                    out[(size_t)row * NCOL + ct * 16 + m16] = RELU ? fmaxf(v, 0.f) : v;
                }
            }
        }
    }
}

// ---------------- aggregation (CSR gather-sum, 4-wide pipelined MLP) ----------------
__global__ void aggregate_kernel(const float* __restrict__ x, const int* __restrict__ row_off,
                                 const int* __restrict__ csr, float* __restrict__ agg, int N) {
    int gw = (blockIdx.x * 256 + threadIdx.x) >> 6;
    int lane = threadIdx.x & 63;
    if (gw >= N) return;
    int beg = row_off[gw], end = row_off[gw + 1];
    int cofs = lane * 2;

    f2 a0 = (f2)0.f, a1 = (f2)0.f, a2 = (f2)0.f, a3 = (f2)0.f;

    int nfull = (end - beg) >> 2;
    int j = beg;
    if (nfull > 0) {
        int s0 = csr[j], s1 = csr[j + 1], s2 = csr[j + 2], s3 = csr[j + 3];
        for (int b = 1; b < nfull; ++b) {
            f2 v0 = *(const f2*)&x[(size_t)s0 * HID + cofs];
            f2 v1 = *(const f2*)&x[(size_t)s1 * HID + cofs];
            f2 v2 = *(const f2*)&x[(size_t)s2 * HID + cofs];
            f2 v3 = *(const f2*)&x[(size_t)s3 * HID + cofs];
            int jn = j + 4;
            s0 = csr[jn]; s1 = csr[jn + 1]; s2 = csr[jn + 2]; s3 = csr[jn + 3];
            a0 += v0; a1 += v1; a2 += v2; a3 += v3;
            j = jn;
        }
        f2 v0 = *(const f2*)&x[(size_t)s0 * HID + cofs];
        f2 v1 = *(const f2*)&x[(size_t)s1 * HID + cofs];
        f2 v2 = *(const f2*)&x[(size_t)s2 * HID + cofs];
        f2 v3 = *(const f2*)&x[(size_t)s3 * HID + cofs];
        a0 += v0; a1 += v1; a2 += v2; a3 += v3;
        j += 4;
    }

    int rem = end - j;
    if (rem > 0) {
        int e1 = end - 1;
        int t0 = csr[j];
        int t1 = csr[min(j + 1, e1)];
        int t2 = csr[min(j + 2, e1)];
        f2 w0 = *(const f2*)&x[(size_t)t0 * HID + cofs];
        f2 w1 = *(const f2*)&x[(size_t)t1 * HID + cofs];
        f2 w2 = *(const f2*)&x[(size_t)t2 * HID + cofs];
        a0 += w0;
        if (rem > 1) a1 += w1;
        if (rem > 2) a2 += w2;
    }

    f2 a = (a0 + a2) + (a1 + a3);
    *(f2*)&agg[(size_t)gw * HID + cofs] = a;
}

// ---------------- edge head ----------------
__global__ void edge_out_kernel(const int* __restrict__ src, const int* __restrict__ dst,
                                const float* __restrict__ pspd, const float* __restrict__ head_b,
                                float* __restrict__ out, int E) {
    int idx = blockIdx.x * blockDim.x + threadIdx.x;
    int e = idx >> 3;
    int c4 = (idx & 7) * 4;
    if (e >= E) return;
    int s = src[e], d = dst[e];
    f4 a = *(const f4*)&pspd[(size_t)s * 64 + c4];
    f4 b = *(const f4*)&pspd[(size_t)d * 64 + 32 + c4];
    f4 hb = *(const f4*)&head_b[c4];
    f4 o = a + b + hb;
    *(f4*)&out[(size_t)e * CLASSES + c4] = o;
}

// ---------------- launcher ----------------

extern "C" void kernel_launch(void* const* d_in, const int* in_sizes, int n_in,
                              void* d_out, int out_size, void* d_ws, size_t ws_size,
                              hipStream_t stream) {
    const float* feat   = (const float*)d_in[0];
    const int*   eidx   = (const int*)d_in[1];
    const float* emb_w  = (const float*)d_in[2];
    const float* emb_b  = (const float*)d_in[3];
    const float* rel_w  = (const float*)d_in[4];
    const float* rel_b  = (const float*)d_in[5];
    const float* root_w = (const float*)d_in[6];
    const float* head_w = (const float*)d_in[7];
    const float* head_b = (const float*)d_in[8];
    float* out = (float*)d_out;

    int N = in_sizes[0] / FEAT;
    int E = in_sizes[1] / 2;
    const int* src = eidx;
    const int* dst = eidx + E;

    // workspace layout: floats, then ints, then ushort weight tables (16B-aligned)
    float* xA  = (float*)d_ws;               // N*128
    float* xB  = xA + (size_t)N * HID;       // N*128
    float* agg = xB + (size_t)N * HID;       // N*128 (pspd reuses as N*64)
    int* counts   = (int*)(agg + (size_t)N * HID);  // N
    int* row_off  = counts + N;                     // N+1
    int* cursor   = row_off + (N + 1);              // N
    int* csr_src  = cursor + N;                     // E
    int* partials = csr_src + E;                    // 256
    int* poff     = partials + 256;                 // 256
    int* iend     = poff + 256;
    // pad int region to 16B boundary
    size_t ioff = (size_t)(iend - (int*)d_ws);
    ioff = (ioff + 3) & ~(size_t)3;
    unsigned short* we_hi = (unsigned short*)((int*)d_ws + ioff);
    unsigned short* we_lo = we_hi + 128 * 256;
    unsigned short* wl_hi = we_lo + 128 * 256;      // 3*128*256
    unsigned short* wl_lo = wl_hi + 3 * 128 * 256;  // 3*128*256
    unsigned short* wp_hi = wl_lo + 3 * 128 * 256;  // 64*128
    unsigned short* wp_lo = wp_hi + 64 * 128;       // 64*128

    int NB = (N + 255) / 256;

    hipMemsetAsync(counts, 0, (size_t)N * sizeof(int), stream);
    count_kernel<<<(E + 255) / 256, 256, 0, stream>>>(dst, counts, E);
    partial_kernel<<<NB, 256, 0, stream>>>(counts, partials, N);
    scan_partials_kernel<<<1, 256, 0, stream>>>(partials, poff, NB);
    scan_final_kernel<<<NB, 256, 0, stream>>>(counts, poff, row_off, cursor, N);
    fill_kernel<<<(E + 255) / 256, 256, 0, stream>>>(src, dst, cursor, csr_src, E);

    prep_emb_kernel<<<(128 * 256 + 255) / 256, 256, 0, stream>>>(emb_w, we_hi, we_lo);
    prep_layer_kernel<<<(3 * 128 * 256 + 255) / 256, 256, 0, stream>>>(rel_w, root_w, wl_hi, wl_lo);
    prep_head_kernel<<<(64 * 128 + 255) / 256, 256, 0, stream>>>(head_w, wp_hi, wp_lo);

    int grid = (N + 127) / 128;
    // embed: x = relu(feat @ emb_w + emb_b)
    gemm_mfma<HID, FEAT, true><<<grid, 256, 0, stream>>>(
        feat, FEAT, nullptr, 0, FEAT, we_hi, we_lo, emb_b, xA, N);

    const float* xin = xA;
    float* xout = xB;
    for (int l = 0; l < LAYERS; ++l) {
        aggregate_kernel<<<(N * 64 + 255) / 256, 256, 0, stream>>>(xin, row_off, csr_src, agg, N);
        gemm_mfma<HID, 2 * HID, true><<<grid, 256, 0, stream>>>(
            agg, HID, xin, HID, HID,
            wl_hi + (size_t)l * 128 * 256, wl_lo + (size_t)l * 128 * 256,
            rel_b + (size_t)l * HID, xout, N);
        float* tmp = (float*)xin; xin = xout; xout = tmp;
    }

    // pspd = x @ Wpp (no bias/relu); reuse agg
    float* pspd = agg;
    gemm_mfma<64, HID, false><<<grid, 256, 0, stream>>>(
        xin, HID, nullptr, 0, HID, wp_hi, wp_lo, nullptr, pspd, N);

    edge_out_kernel<<<((size_t)E * 8 + 255) / 256, 256, 0, stream>>>(src, dst, pspd, head_b, out, E);
}